// Round 11
// baseline (71.894 us; speedup 1.0000x reference)
//
#include <hip/hip_runtime.h>
#include <math.h>
#include <stdint.h>

#define B_     32
#define L_     16384
#define C_     128
#define KTOP   64
#define NCOL   (B_ * C_)     // 4096 columns
#define CAPMAX 256           // per-column candidate capacity (4 slots/lane * 64 lanes)
#define CSTR   32            // cnt stride in ints: one counter per 128 B L2 line
#define LSLOT  16            // LDS candidate slots per column per block
#define T0     2.42f         // P(N(0,1)>T0)=0.00776 -> mean n~127, sd~11.2
                             // P(n<64) ~ 7.6e-9/col (3e-5 overall); P(n>256) ~ 0 (11.5 sigma)

typedef float f32x4 __attribute__((ext_vector_type(4)));

// pack (value, index): high32 = float bits (v > T0 > 0 so bit pattern is
// monotonic in value), low32 = index. u64 max == lexicographic (value, index)
// max == JAX stable-argsort tie rule (largest indices win ties).
__device__ __forceinline__ uint64_t pack_cand(float v, int l) {
    return ((uint64_t)__float_as_uint(v) << 32) | (uint32_t)l;
}

// lexicographic (value, index) less-than (fallback path only)
__device__ __forceinline__ bool lex_lt(float v1, int i1, float v2, int i2) {
    return (v1 < v2) || ((v1 == v2) && (i1 < i2));
}

// Zero the padded per-column counters (512 KB).
__global__ __launch_bounds__(256) void k_zero(int* __restrict__ cnt) {
    cnt[blockIdx.x * 256 + threadIdx.x] = 0;
}

// Pass 1: stream x with 4 nontemporal float4 loads in flight (read-once data
// -- keep it out of L2 so the hot cand/cnt lines stay resident), one combined
// 16-element pre-test (88% of iterations take a single branch), LDS-batched
// compact; one padded global atomic per (block, column).
__global__ __launch_bounds__(256) void k_filter(const float* __restrict__ x,
                                                int* __restrict__ cnt,
                                                uint64_t* __restrict__ cand,
                                                int cap) {
    __shared__ int      lcnt[C_];
    __shared__ uint64_t lbuf[C_][LSLOT + 1];   // +1: break 128B-stride bank aliasing

    const int tid = threadIdx.x;
    const int b   = blockIdx.y;
    const int l0  = blockIdx.x * 256;
    const int r   = tid >> 5;                  // 0..7 row within group
    const int c4  = tid & 31;                  // float4 slot within row
    const f32x4* xc = (const f32x4*)x + (size_t)b * L_ * (C_ / 4) + c4;
    const int clbase = c4 * 4;

    if (tid < C_) lcnt[tid] = 0;
    __syncthreads();

    for (int l = l0 + r; l < l0 + 256; l += 32) {
        f32x4 v0 = __builtin_nontemporal_load(&xc[(l +  0) * (C_ / 4)]);
        f32x4 v1 = __builtin_nontemporal_load(&xc[(l +  8) * (C_ / 4)]);
        f32x4 v2 = __builtin_nontemporal_load(&xc[(l + 16) * (C_ / 4)]);
        f32x4 v3 = __builtin_nontemporal_load(&xc[(l + 24) * (C_ / 4)]);
        // combined 16-element pre-test: single branch in the all-miss case
        float m0 = fmaxf(fmaxf(v0.x, v0.y), fmaxf(v0.z, v0.w));
        float m1 = fmaxf(fmaxf(v1.x, v1.y), fmaxf(v1.z, v1.w));
        float m2 = fmaxf(fmaxf(v2.x, v2.y), fmaxf(v2.z, v2.w));
        float m3 = fmaxf(fmaxf(v3.x, v3.y), fmaxf(v3.z, v3.w));
        if (fmaxf(fmaxf(m0, m1), fmaxf(m2, m3)) > T0) {
#pragma unroll
            for (int h = 0; h < 4; ++h) {
                const f32x4 v = (h == 0) ? v0 : (h == 1) ? v1 : (h == 2) ? v2 : v3;
                const float mq = (h == 0) ? m0 : (h == 1) ? m1 : (h == 2) ? m2 : m3;
                const int   lr = l + h * 8;
                if (mq > T0) {
#pragma unroll
                    for (int j = 0; j < 4; ++j) {
                        float vv = (j == 0) ? v.x : (j == 1) ? v.y : (j == 2) ? v.z : v.w;
                        if (vv > T0) {
                            int cl = clbase + j;
                            int p  = atomicAdd(&lcnt[cl], 1);
                            if (p < LSLOT) {
                                lbuf[cl][p] = pack_cand(vv, lr);
                            } else {  // rare overflow: direct global append
                                int g = atomicAdd(&cnt[(b * C_ + cl) * CSTR], 1);
                                if (g < cap) cand[(size_t)(b * C_ + cl) * cap + g] = pack_cand(vv, lr);
                            }
                        }
                    }
                }
            }
        }
    }
    __syncthreads();

    if (tid < C_) {
        int m = lcnt[tid];
        m = (m > LSLOT) ? LSLOT : m;
        if (m > 0) {
            int col  = b * C_ + tid;
            int base = atomicAdd(&cnt[col * CSTR], m);
            for (int j = 0; j < m; ++j) {
                int p = base + j;
                if (p < cap) cand[(size_t)col * cap + p] = lbuf[tid][j];
            }
        }
    }
}

// Pass 2 (UNCHANGED from R9): ONE WAVE per column. Ballot-based exact
// selection: binary-search the 64th-largest value bits (VALU-only), break
// ties by index (largest indices win, per JAX stable argsort), compact the
// exactly-64 winners into LDS via ballot-prefix slots, then a 21-level
// ascending bitonic sort by index -> lane i = out row i.
__global__ __launch_bounds__(256) void k_select(const float* __restrict__ x,
                                                const int* __restrict__ cnt,
                                                const uint64_t* __restrict__ cand,
                                                float* __restrict__ out,
                                                int cap) {
    __shared__ uint64_t wbuf[4][KTOP];

    const int wave = threadIdx.x >> 6;           // 0..3
    const int lane = threadIdx.x & 63;
    const int col  = blockIdx.x * 4 + wave;
    const int b    = col >> 7;
    const int c    = col & (C_ - 1);

    const int n = (cap > 0) ? cnt[col * CSTR] : 0;

    uint64_t key2;

    if (n >= KTOP && n <= cap) {
        // ---- fast path: candidates into registers (4 slots/lane) ----
        uint32_t vb[4], ix[4];
#pragma unroll
        for (int i = 0; i < 4; ++i) {
            int p = lane + i * 64;
            uint64_t s = (p < n) ? cand[(size_t)col * cap + p] : 0ull;  // 0 = below all
            vb[i] = (uint32_t)(s >> 32);
            ix[i] = (uint32_t)s;
        }
        // exact upper bound: wave-max of value bits
        uint32_t vmax = max(max(vb[0], vb[1]), max(vb[2], vb[3]));
#pragma unroll
        for (int off = 32; off; off >>= 1)
            vmax = max(vmax, (uint32_t)__shfl_xor((int)vmax, off, 64));
        // binary search on value bits: C(p) = #{vb > p}; C(lo)>=64 > C(hi)
        uint32_t lo = __float_as_uint(T0), hi = vmax + 1;
        while (hi - lo > 1) {
            uint32_t mid = lo + ((hi - lo) >> 1);
            int cgt = 0;
#pragma unroll
            for (int i = 0; i < 4; ++i)
                cgt += (int)__popcll(__ballot(vb[i] > mid));
            if (cgt >= KTOP) lo = mid; else hi = mid;
        }
        const uint32_t v64 = lo + 1;   // value bits of the 64th-largest (val,idx) key
        int cgt = 0;
#pragma unroll
        for (int i = 0; i < 4; ++i)
            cgt += (int)__popcll(__ballot(vb[i] > v64));
        const int m = KTOP - cgt;      // winners still needed among ties (>= 1)
        // binary search on index among ties: largest thr with #{tie && idx>=thr} >= m
        uint32_t tlo = 0, thi = L_;
        while (thi - tlo > 1) {
            uint32_t mid = tlo + ((thi - tlo) >> 1);
            int ct = 0;
#pragma unroll
            for (int i = 0; i < 4; ++i)
                ct += (int)__popcll(__ballot(vb[i] == v64 && ix[i] >= mid));
            if (ct >= m) tlo = mid; else thi = mid;
        }
        // compact the 64 winners into LDS at ballot-prefix slots (no atomics,
        // no block barrier -- per-wave buffer, in-order LDS per wave)
        volatile uint64_t* wb = wbuf[wave];
        int base = 0;
#pragma unroll
        for (int i = 0; i < 4; ++i) {
            const bool win = (vb[i] > v64) || (vb[i] == v64 && ix[i] >= tlo);
            const uint64_t msk = __ballot(win);
            if (win) {
                int slot = base + (int)__popcll(msk & ((1ull << lane) - 1ull));
                wb[slot] = ((uint64_t)ix[i] << 32) | vb[i];
            }
            base += (int)__popcll(msk);
        }
        __builtin_amdgcn_wave_barrier();
        key2 = wb[lane];
    } else {
        // ---- exact fallback: lexicographic-descent argmax, 64 rounds ----
        const float* xc = x + (size_t)b * L_ * C_ + c;
        float pv = INFINITY;
        int   pi = 0x7fffffff;
        float keepv = 0.0f;
        int   keepi = 0;
        for (int k = 0; k < KTOP; ++k) {
            float bv = -INFINITY;
            int   bi = -1;
            for (int l = lane; l < L_; l += 64) {
                float vv = xc[(size_t)l * C_];
                if (lex_lt(vv, l, pv, pi) && lex_lt(bv, bi, vv, l)) {
                    bv = vv; bi = l;
                }
            }
#pragma unroll
            for (int off = 32; off; off >>= 1) {
                float ov = __shfl_xor(bv, off, 64);
                int   oi = __shfl_xor(bi, off, 64);
                if (lex_lt(bv, bi, ov, oi)) { bv = ov; bi = oi; }
            }
            pv = bv; pi = bi;
            if (lane == k) { keepv = bv; keepi = bi; }
        }
        key2 = ((uint64_t)(uint32_t)keepi << 32) | __float_as_uint(keepv);
    }

    // temporal reorder: 64-lane ascending bitonic sort on key2 = (index, value)
    // (indices unique -> strict order). Lane i then holds output row i.
#pragma unroll
    for (int k = 2; k <= 64; k <<= 1) {
#pragma unroll
        for (int j = k >> 1; j >= 1; j >>= 1) {
            const bool upper = (lane & j) != 0;
            uint64_t o = __shfl_xor((unsigned long long)key2, j, 64);
            const bool km = ((lane & k) != 0);      // ascending block?
            const bool take_max = (km != upper);
            const bool gt = key2 > o;
            key2 = (take_max == gt) ? key2 : o;
        }
    }
    out[((size_t)b * KTOP + lane) * C_ + c] =
        __uint_as_float((uint32_t)(key2 & 0xffffffffull));
}

extern "C" void kernel_launch(void* const* d_in, const int* in_sizes, int n_in,
                              void* d_out, int out_size, void* d_ws, size_t ws_size,
                              hipStream_t stream) {
    (void)in_sizes; (void)n_in; (void)out_size;
    const float* x  = (const float*)d_in[0];
    float*      out = (float*)d_out;

    int*   cnt       = (int*)d_ws;
    size_t cnt_bytes = (size_t)NCOL * CSTR * sizeof(int);   // 512 KB, padded

    // size the candidate buffer from the workspace we actually have
    int cap = 0;
    if (ws_size > cnt_bytes) {
        size_t rem = ws_size - cnt_bytes;
        size_t c   = rem / ((size_t)NCOL * 8);  // 8 B per packed slot
        cap = (c > CAPMAX) ? CAPMAX : (int)c;
    }
    uint64_t* cand = (uint64_t*)((char*)d_ws + cnt_bytes);

    if (cap >= KTOP) {
        k_zero<<<(NCOL * CSTR) / 256, 256, 0, stream>>>(cnt);
        dim3 g1(L_ / 256, B_);
        k_filter<<<g1, 256, 0, stream>>>(x, cnt, cand, cap);
    } else {
        cap = 0;  // workspace too small: k_select takes exact fallback for all
    }

    k_select<<<NCOL / 4, 256, 0, stream>>>(x, cnt, cand, out, cap);
}

// Round 12
// 64.148 us; speedup vs baseline: 1.1208x; 1.1208x over previous
//
#include <hip/hip_runtime.h>
#include <math.h>
#include <stdint.h>

#define B_     32
#define L_     16384
#define C_     128
#define KTOP   64
#define NCOL   (B_ * C_)     // 4096 columns
#define CAPMAX 256           // per-column candidate capacity (4 slots/lane * 64 lanes)
#define CSTR   32            // cnt stride in ints: one counter per 128 B L2 line
#define ROWS   512           // rows per filter block (R12: was 256; halves line-sharing)
#define LSLOT  24            // LDS candidate slots per column per block (mean 4, P(>24)~1e-13)
#define T0     2.42f         // P(N(0,1)>T0)=0.00776 -> mean n~127, sd~11.2
                             // P(n<64) ~ 7.6e-9/col (3e-5 overall); P(n>256) ~ 0 (11.5 sigma)

typedef float f32x4 __attribute__((ext_vector_type(4)));

// pack (value, index): high32 = float bits (v > T0 > 0 so bit pattern is
// monotonic in value), low32 = index. u64 max == lexicographic (value, index)
// max == JAX stable-argsort tie rule (largest indices win ties).
__device__ __forceinline__ uint64_t pack_cand(float v, int l) {
    return ((uint64_t)__float_as_uint(v) << 32) | (uint32_t)l;
}

// lexicographic (value, index) less-than (fallback path only)
__device__ __forceinline__ bool lex_lt(float v1, int i1, float v2, int i2) {
    return (v1 < v2) || ((v1 == v2) && (i1 < i2));
}

// Zero the padded per-column counters (512 KB).
__global__ __launch_bounds__(256) void k_zero(int* __restrict__ cnt) {
    cnt[blockIdx.x * 256 + threadIdx.x] = 0;
}

// Pass 1 (R10 core, ROWS=512): stream x with 4 float4 loads in flight
// (plain loads -- NT regressed in R11), per-quad pre-test, LDS-batched
// compact; one padded global atomic per (block, column). 512 rows/block
// halves the number of blocks dirtying each cand cache line (cross-XCD
// write-allocate ping-pong) and halves the global atomic count.
__global__ __launch_bounds__(256) void k_filter(const float* __restrict__ x,
                                                int* __restrict__ cnt,
                                                uint64_t* __restrict__ cand,
                                                int cap) {
    __shared__ int      lcnt[C_];
    __shared__ uint64_t lbuf[C_][LSLOT + 1];   // +1: break 128B-stride bank aliasing

    const int tid = threadIdx.x;
    const int b   = blockIdx.y;
    const int l0  = blockIdx.x * ROWS;
    const int r   = tid >> 5;                  // 0..7 row within group
    const int c4  = tid & 31;                  // float4 slot within row
    const f32x4* xc = (const f32x4*)x + (size_t)b * L_ * (C_ / 4) + c4;
    const int clbase = c4 * 4;

    if (tid < C_) lcnt[tid] = 0;
    __syncthreads();

    for (int l = l0 + r; l < l0 + ROWS; l += 32) {
        f32x4 v0 = xc[(l +  0) * (C_ / 4)];
        f32x4 v1 = xc[(l +  8) * (C_ / 4)];
        f32x4 v2 = xc[(l + 16) * (C_ / 4)];
        f32x4 v3 = xc[(l + 24) * (C_ / 4)];
#pragma unroll
        for (int h = 0; h < 4; ++h) {
            const f32x4 v = (h == 0) ? v0 : (h == 1) ? v1 : (h == 2) ? v2 : v3;
            const int   lr = l + h * 8;
            // quad-max pre-test: skip per-element branch blocks when no hit
            if (fmaxf(fmaxf(v.x, v.y), fmaxf(v.z, v.w)) > T0) {
#pragma unroll
                for (int j = 0; j < 4; ++j) {
                    float vv = (j == 0) ? v.x : (j == 1) ? v.y : (j == 2) ? v.z : v.w;
                    if (vv > T0) {
                        int cl = clbase + j;
                        int p  = atomicAdd(&lcnt[cl], 1);
                        if (p < LSLOT) {
                            lbuf[cl][p] = pack_cand(vv, lr);
                        } else {  // rare overflow: direct global append
                            int g = atomicAdd(&cnt[(b * C_ + cl) * CSTR], 1);
                            if (g < cap) cand[(size_t)(b * C_ + cl) * cap + g] = pack_cand(vv, lr);
                        }
                    }
                }
            }
        }
    }
    __syncthreads();

    if (tid < C_) {
        int m = lcnt[tid];
        m = (m > LSLOT) ? LSLOT : m;
        if (m > 0) {
            int col  = b * C_ + tid;
            int base = atomicAdd(&cnt[col * CSTR], m);
            for (int j = 0; j < m; ++j) {
                int p = base + j;
                if (p < cap) cand[(size_t)col * cap + p] = lbuf[tid][j];
            }
        }
    }
}

// Pass 2 (UNCHANGED from R9): ONE WAVE per column. Ballot-based exact
// selection: binary-search the 64th-largest value bits (VALU-only), break
// ties by index (largest indices win, per JAX stable argsort), compact the
// exactly-64 winners into LDS via ballot-prefix slots, then a 21-level
// ascending bitonic sort by index -> lane i = out row i.
__global__ __launch_bounds__(256) void k_select(const float* __restrict__ x,
                                                const int* __restrict__ cnt,
                                                const uint64_t* __restrict__ cand,
                                                float* __restrict__ out,
                                                int cap) {
    __shared__ uint64_t wbuf[4][KTOP];

    const int wave = threadIdx.x >> 6;           // 0..3
    const int lane = threadIdx.x & 63;
    const int col  = blockIdx.x * 4 + wave;
    const int b    = col >> 7;
    const int c    = col & (C_ - 1);

    const int n = (cap > 0) ? cnt[col * CSTR] : 0;

    uint64_t key2;

    if (n >= KTOP && n <= cap) {
        // ---- fast path: candidates into registers (4 slots/lane) ----
        uint32_t vb[4], ix[4];
#pragma unroll
        for (int i = 0; i < 4; ++i) {
            int p = lane + i * 64;
            uint64_t s = (p < n) ? cand[(size_t)col * cap + p] : 0ull;  // 0 = below all
            vb[i] = (uint32_t)(s >> 32);
            ix[i] = (uint32_t)s;
        }
        // exact upper bound: wave-max of value bits
        uint32_t vmax = max(max(vb[0], vb[1]), max(vb[2], vb[3]));
#pragma unroll
        for (int off = 32; off; off >>= 1)
            vmax = max(vmax, (uint32_t)__shfl_xor((int)vmax, off, 64));
        // binary search on value bits: C(p) = #{vb > p}; C(lo)>=64 > C(hi)
        uint32_t lo = __float_as_uint(T0), hi = vmax + 1;
        while (hi - lo > 1) {
            uint32_t mid = lo + ((hi - lo) >> 1);
            int cgt = 0;
#pragma unroll
            for (int i = 0; i < 4; ++i)
                cgt += (int)__popcll(__ballot(vb[i] > mid));
            if (cgt >= KTOP) lo = mid; else hi = mid;
        }
        const uint32_t v64 = lo + 1;   // value bits of the 64th-largest (val,idx) key
        int cgt = 0;
#pragma unroll
        for (int i = 0; i < 4; ++i)
            cgt += (int)__popcll(__ballot(vb[i] > v64));
        const int m = KTOP - cgt;      // winners still needed among ties (>= 1)
        // binary search on index among ties: largest thr with #{tie && idx>=thr} >= m
        uint32_t tlo = 0, thi = L_;
        while (thi - tlo > 1) {
            uint32_t mid = tlo + ((thi - tlo) >> 1);
            int ct = 0;
#pragma unroll
            for (int i = 0; i < 4; ++i)
                ct += (int)__popcll(__ballot(vb[i] == v64 && ix[i] >= mid));
            if (ct >= m) tlo = mid; else thi = mid;
        }
        // compact the 64 winners into LDS at ballot-prefix slots (no atomics,
        // no block barrier -- per-wave buffer, in-order LDS per wave)
        volatile uint64_t* wb = wbuf[wave];
        int base = 0;
#pragma unroll
        for (int i = 0; i < 4; ++i) {
            const bool win = (vb[i] > v64) || (vb[i] == v64 && ix[i] >= tlo);
            const uint64_t msk = __ballot(win);
            if (win) {
                int slot = base + (int)__popcll(msk & ((1ull << lane) - 1ull));
                wb[slot] = ((uint64_t)ix[i] << 32) | vb[i];
            }
            base += (int)__popcll(msk);
        }
        __builtin_amdgcn_wave_barrier();
        key2 = wb[lane];
    } else {
        // ---- exact fallback: lexicographic-descent argmax, 64 rounds ----
        const float* xc = x + (size_t)b * L_ * C_ + c;
        float pv = INFINITY;
        int   pi = 0x7fffffff;
        float keepv = 0.0f;
        int   keepi = 0;
        for (int k = 0; k < KTOP; ++k) {
            float bv = -INFINITY;
            int   bi = -1;
            for (int l = lane; l < L_; l += 64) {
                float vv = xc[(size_t)l * C_];
                if (lex_lt(vv, l, pv, pi) && lex_lt(bv, bi, vv, l)) {
                    bv = vv; bi = l;
                }
            }
#pragma unroll
            for (int off = 32; off; off >>= 1) {
                float ov = __shfl_xor(bv, off, 64);
                int   oi = __shfl_xor(bi, off, 64);
                if (lex_lt(bv, bi, ov, oi)) { bv = ov; bi = oi; }
            }
            pv = bv; pi = bi;
            if (lane == k) { keepv = bv; keepi = bi; }
        }
        key2 = ((uint64_t)(uint32_t)keepi << 32) | __float_as_uint(keepv);
    }

    // temporal reorder: 64-lane ascending bitonic sort on key2 = (index, value)
    // (indices unique -> strict order). Lane i then holds output row i.
#pragma unroll
    for (int k = 2; k <= 64; k <<= 1) {
#pragma unroll
        for (int j = k >> 1; j >= 1; j >>= 1) {
            const bool upper = (lane & j) != 0;
            uint64_t o = __shfl_xor((unsigned long long)key2, j, 64);
            const bool km = ((lane & k) != 0);      // ascending block?
            const bool take_max = (km != upper);
            const bool gt = key2 > o;
            key2 = (take_max == gt) ? key2 : o;
        }
    }
    out[((size_t)b * KTOP + lane) * C_ + c] =
        __uint_as_float((uint32_t)(key2 & 0xffffffffull));
}

extern "C" void kernel_launch(void* const* d_in, const int* in_sizes, int n_in,
                              void* d_out, int out_size, void* d_ws, size_t ws_size,
                              hipStream_t stream) {
    (void)in_sizes; (void)n_in; (void)out_size;
    const float* x  = (const float*)d_in[0];
    float*      out = (float*)d_out;

    int*   cnt       = (int*)d_ws;
    size_t cnt_bytes = (size_t)NCOL * CSTR * sizeof(int);   // 512 KB, padded

    // size the candidate buffer from the workspace we actually have
    int cap = 0;
    if (ws_size > cnt_bytes) {
        size_t rem = ws_size - cnt_bytes;
        size_t c   = rem / ((size_t)NCOL * 8);  // 8 B per packed slot
        cap = (c > CAPMAX) ? CAPMAX : (int)c;
    }
    uint64_t* cand = (uint64_t*)((char*)d_ws + cnt_bytes);

    if (cap >= KTOP) {
        k_zero<<<(NCOL * CSTR) / 256, 256, 0, stream>>>(cnt);
        dim3 g1(L_ / ROWS, B_);
        k_filter<<<g1, 256, 0, stream>>>(x, cnt, cand, cap);
    } else {
        cap = 0;  // workspace too small: k_select takes exact fallback for all
    }

    k_select<<<NCOL / 4, 256, 0, stream>>>(x, cnt, cand, out, cap);
}

// Round 13
// 62.805 us; speedup vs baseline: 1.1447x; 1.0214x over previous
//
#include <hip/hip_runtime.h>
#include <math.h>
#include <stdint.h>

#define B_     32
#define L_     16384
#define C_     128
#define KTOP   64
#define NCOL   (B_ * C_)     // 4096 columns
#define CAPMAX 256           // per-column candidate capacity (4 slots/lane * 64 lanes)
#define CSTR   32            // cnt stride in ints: one counter per 128 B L2 line
#define ROWS   512           // rows per filter block
#define LSLOT  24            // LDS candidate slots per column per block (mean 4, P(>24)~1e-13)
#define T0     2.42f         // P(N(0,1)>T0)=0.00776 -> mean n~127, sd~11.2
                             // P(n<64) ~ 7.6e-9/col (3e-5 overall); P(n>256) ~ 0 (11.5 sigma)

typedef float f32x4 __attribute__((ext_vector_type(4)));

// XCD-affinity swizzle: batch b's blocks all land on XCD b%8 (default
// dispatch round-robins wgid%8 across the 8 XCDs). Keeps each batch's hot
// cnt lines + cand regions in ONE XCD's L2 (1 MB/XCD, fits 4 MB) instead of
// ping-ponging across non-coherent L2s on every global atomic/append.

// pack (value, index): high32 = float bits (v > T0 > 0 so bit pattern is
// monotonic in value), low32 = index. u64 max == lexicographic (value, index)
// max == JAX stable-argsort tie rule (largest indices win ties).
__device__ __forceinline__ uint64_t pack_cand(float v, int l) {
    return ((uint64_t)__float_as_uint(v) << 32) | (uint32_t)l;
}

// lexicographic (value, index) less-than (fallback path only)
__device__ __forceinline__ bool lex_lt(float v1, int i1, float v2, int i2) {
    return (v1 < v2) || ((v1 == v2) && (i1 < i2));
}

// Zero the padded per-column counters (512 KB). 512 blocks, XCD-swizzled so
// each cnt line is zeroed from (and parked in) the XCD that will own it.
__global__ __launch_bounds__(256) void k_zero(int* __restrict__ cnt) {
    const int wg    = blockIdx.x;
    const int xcd   = wg & 7;
    const int inner = wg >> 3;
    const int z     = inner & 15;        // 16 chunks of 8 columns per batch
    const int b     = (inner >> 4) * 8 + xcd;
    const int col   = b * C_ + z * 8 + (threadIdx.x >> 5);
    cnt[col * CSTR + (threadIdx.x & 31)] = 0;
}

// Pass 1 (R12 core + XCD swizzle): stream x with 4 float4 loads in flight,
// per-quad pre-test, LDS-batched compact; one padded global atomic per
// (block, column). All 32 row-chunk blocks of a batch share one XCD.
__global__ __launch_bounds__(256) void k_filter(const float* __restrict__ x,
                                                int* __restrict__ cnt,
                                                uint64_t* __restrict__ cand,
                                                int cap) {
    __shared__ int      lcnt[C_];
    __shared__ uint64_t lbuf[C_][LSLOT + 1];   // +1: break 128B-stride bank aliasing

    const int wg    = blockIdx.x;
    const int xcd   = wg & 7;
    const int inner = wg >> 3;
    const int rx    = inner & 31;              // row chunk 0..31
    const int b     = (inner >> 5) * 8 + xcd;  // batch, pinned to XCD b%8

    const int tid = threadIdx.x;
    const int l0  = rx * ROWS;
    const int r   = tid >> 5;                  // 0..7 row within group
    const int c4  = tid & 31;                  // float4 slot within row
    const f32x4* xc = (const f32x4*)x + (size_t)b * L_ * (C_ / 4) + c4;
    const int clbase = c4 * 4;

    if (tid < C_) lcnt[tid] = 0;
    __syncthreads();

    for (int l = l0 + r; l < l0 + ROWS; l += 32) {
        f32x4 v0 = xc[(l +  0) * (C_ / 4)];
        f32x4 v1 = xc[(l +  8) * (C_ / 4)];
        f32x4 v2 = xc[(l + 16) * (C_ / 4)];
        f32x4 v3 = xc[(l + 24) * (C_ / 4)];
#pragma unroll
        for (int h = 0; h < 4; ++h) {
            const f32x4 v = (h == 0) ? v0 : (h == 1) ? v1 : (h == 2) ? v2 : v3;
            const int   lr = l + h * 8;
            // quad-max pre-test: skip per-element branch blocks when no hit
            if (fmaxf(fmaxf(v.x, v.y), fmaxf(v.z, v.w)) > T0) {
#pragma unroll
                for (int j = 0; j < 4; ++j) {
                    float vv = (j == 0) ? v.x : (j == 1) ? v.y : (j == 2) ? v.z : v.w;
                    if (vv > T0) {
                        int cl = clbase + j;
                        int p  = atomicAdd(&lcnt[cl], 1);
                        if (p < LSLOT) {
                            lbuf[cl][p] = pack_cand(vv, lr);
                        } else {  // rare overflow: direct global append
                            int g = atomicAdd(&cnt[(b * C_ + cl) * CSTR], 1);
                            if (g < cap) cand[(size_t)(b * C_ + cl) * cap + g] = pack_cand(vv, lr);
                        }
                    }
                }
            }
        }
    }
    __syncthreads();

    if (tid < C_) {
        int m = lcnt[tid];
        m = (m > LSLOT) ? LSLOT : m;
        if (m > 0) {
            int col  = b * C_ + tid;
            int base = atomicAdd(&cnt[col * CSTR], m);
            for (int j = 0; j < m; ++j) {
                int p = base + j;
                if (p < cap) cand[(size_t)col * cap + p] = lbuf[tid][j];
            }
        }
    }
}

// Pass 2 (R9 algorithm + XCD swizzle): ONE WAVE per column. Ballot-based
// exact selection; select blocks for batch b run on XCD b%8 so cand/cnt
// reads are local-L2 hits.
__global__ __launch_bounds__(256) void k_select(const float* __restrict__ x,
                                                const int* __restrict__ cnt,
                                                const uint64_t* __restrict__ cand,
                                                float* __restrict__ out,
                                                int cap) {
    __shared__ uint64_t wbuf[4][KTOP];

    const int wg    = blockIdx.x;
    const int xcd   = wg & 7;
    const int inner = wg >> 3;
    const int cw    = inner & 31;              // column group 0..31 (4 cols each)
    const int b     = (inner >> 5) * 8 + xcd;  // batch, pinned to XCD b%8

    const int wave = threadIdx.x >> 6;           // 0..3
    const int lane = threadIdx.x & 63;
    const int c    = cw * 4 + wave;
    const int col  = b * C_ + c;

    const int n = (cap > 0) ? cnt[col * CSTR] : 0;

    uint64_t key2;

    if (n >= KTOP && n <= cap) {
        // ---- fast path: candidates into registers (4 slots/lane) ----
        uint32_t vb[4], ix[4];
#pragma unroll
        for (int i = 0; i < 4; ++i) {
            int p = lane + i * 64;
            uint64_t s = (p < n) ? cand[(size_t)col * cap + p] : 0ull;  // 0 = below all
            vb[i] = (uint32_t)(s >> 32);
            ix[i] = (uint32_t)s;
        }
        // exact upper bound: wave-max of value bits
        uint32_t vmax = max(max(vb[0], vb[1]), max(vb[2], vb[3]));
#pragma unroll
        for (int off = 32; off; off >>= 1)
            vmax = max(vmax, (uint32_t)__shfl_xor((int)vmax, off, 64));
        // binary search on value bits: C(p) = #{vb > p}; C(lo)>=64 > C(hi)
        uint32_t lo = __float_as_uint(T0), hi = vmax + 1;
        while (hi - lo > 1) {
            uint32_t mid = lo + ((hi - lo) >> 1);
            int cgt = 0;
#pragma unroll
            for (int i = 0; i < 4; ++i)
                cgt += (int)__popcll(__ballot(vb[i] > mid));
            if (cgt >= KTOP) lo = mid; else hi = mid;
        }
        const uint32_t v64 = lo + 1;   // value bits of the 64th-largest (val,idx) key
        int cgt = 0;
#pragma unroll
        for (int i = 0; i < 4; ++i)
            cgt += (int)__popcll(__ballot(vb[i] > v64));
        const int m = KTOP - cgt;      // winners still needed among ties (>= 1)
        // binary search on index among ties: largest thr with #{tie && idx>=thr} >= m
        uint32_t tlo = 0, thi = L_;
        while (thi - tlo > 1) {
            uint32_t mid = tlo + ((thi - tlo) >> 1);
            int ct = 0;
#pragma unroll
            for (int i = 0; i < 4; ++i)
                ct += (int)__popcll(__ballot(vb[i] == v64 && ix[i] >= mid));
            if (ct >= m) tlo = mid; else thi = mid;
        }
        // compact the 64 winners into LDS at ballot-prefix slots (no atomics,
        // no block barrier -- per-wave buffer, in-order LDS per wave)
        volatile uint64_t* wb = wbuf[wave];
        int base = 0;
#pragma unroll
        for (int i = 0; i < 4; ++i) {
            const bool win = (vb[i] > v64) || (vb[i] == v64 && ix[i] >= tlo);
            const uint64_t msk = __ballot(win);
            if (win) {
                int slot = base + (int)__popcll(msk & ((1ull << lane) - 1ull));
                wb[slot] = ((uint64_t)ix[i] << 32) | vb[i];
            }
            base += (int)__popcll(msk);
        }
        __builtin_amdgcn_wave_barrier();
        key2 = wb[lane];
    } else {
        // ---- exact fallback: lexicographic-descent argmax, 64 rounds ----
        const float* xc = x + (size_t)b * L_ * C_ + c;
        float pv = INFINITY;
        int   pi = 0x7fffffff;
        float keepv = 0.0f;
        int   keepi = 0;
        for (int k = 0; k < KTOP; ++k) {
            float bv = -INFINITY;
            int   bi = -1;
            for (int l = lane; l < L_; l += 64) {
                float vv = xc[(size_t)l * C_];
                if (lex_lt(vv, l, pv, pi) && lex_lt(bv, bi, vv, l)) {
                    bv = vv; bi = l;
                }
            }
#pragma unroll
            for (int off = 32; off; off >>= 1) {
                float ov = __shfl_xor(bv, off, 64);
                int   oi = __shfl_xor(bi, off, 64);
                if (lex_lt(bv, bi, ov, oi)) { bv = ov; bi = oi; }
            }
            pv = bv; pi = bi;
            if (lane == k) { keepv = bv; keepi = bi; }
        }
        key2 = ((uint64_t)(uint32_t)keepi << 32) | __float_as_uint(keepv);
    }

    // temporal reorder: 64-lane ascending bitonic sort on key2 = (index, value)
    // (indices unique -> strict order). Lane i then holds output row i.
#pragma unroll
    for (int k = 2; k <= 64; k <<= 1) {
#pragma unroll
        for (int j = k >> 1; j >= 1; j >>= 1) {
            const bool upper = (lane & j) != 0;
            uint64_t o = __shfl_xor((unsigned long long)key2, j, 64);
            const bool km = ((lane & k) != 0);      // ascending block?
            const bool take_max = (km != upper);
            const bool gt = key2 > o;
            key2 = (take_max == gt) ? key2 : o;
        }
    }
    out[((size_t)b * KTOP + lane) * C_ + c] =
        __uint_as_float((uint32_t)(key2 & 0xffffffffull));
}

extern "C" void kernel_launch(void* const* d_in, const int* in_sizes, int n_in,
                              void* d_out, int out_size, void* d_ws, size_t ws_size,
                              hipStream_t stream) {
    (void)in_sizes; (void)n_in; (void)out_size;
    const float* x  = (const float*)d_in[0];
    float*      out = (float*)d_out;

    int*   cnt       = (int*)d_ws;
    size_t cnt_bytes = (size_t)NCOL * CSTR * sizeof(int);   // 512 KB, padded

    // size the candidate buffer from the workspace we actually have
    int cap = 0;
    if (ws_size > cnt_bytes) {
        size_t rem = ws_size - cnt_bytes;
        size_t c   = rem / ((size_t)NCOL * 8);  // 8 B per packed slot
        cap = (c > CAPMAX) ? CAPMAX : (int)c;
    }
    uint64_t* cand = (uint64_t*)((char*)d_ws + cnt_bytes);

    if (cap >= KTOP) {
        k_zero<<<(NCOL * CSTR) / 256, 256, 0, stream>>>(cnt);
        k_filter<<<(L_ / ROWS) * B_, 256, 0, stream>>>(x, cnt, cand, cap);
    } else {
        cap = 0;  // workspace too small: k_select takes exact fallback for all
    }

    k_select<<<NCOL / 4, 256, 0, stream>>>(x, cnt, cand, out, cap);
}